// Round 1
// baseline (440.371 us; speedup 1.0000x reference)
//
#include <hip/hip_runtime.h>
#include <hip/hip_bf16.h>
#include <cstdint>

// Problem: x[4,2048,1024] fp32; qkv = x@W_in^T+b_in; 16-head causal attention
// (dh=64); out = attn@W_out^T + b_out -> fp32 [4,2048,1024].
// Strategy: bf16 MFMA everywhere (threshold 7.4e-2 allows it), fp32 accumulate.

typedef float  floatx4  __attribute__((ext_vector_type(4)));
typedef __bf16 bf16x8   __attribute__((ext_vector_type(8)));
typedef __bf16 bf16x4   __attribute__((ext_vector_type(4)));
typedef unsigned short ushortx8 __attribute__((ext_vector_type(8)));

#define MFMA16(a,b,c) __builtin_amdgcn_mfma_f32_16x16x32_bf16(a, b, c, 0, 0, 0)

__device__ __forceinline__ void gload_lds16(const void* g, void* l) {
  __builtin_amdgcn_global_load_lds(
      (__attribute__((address_space(1))) void*)(g),
      (__attribute__((address_space(3))) void*)(l), 16, 0, 0);
}

// ---------------------------------------------------------------- cast fp32->bf16
__global__ __launch_bounds__(256) void cast_kernel(
    const float* __restrict__ in, __bf16* __restrict__ out, int n4) {
  int i = blockIdx.x * 256 + threadIdx.x;
  if (i < n4) {
    const float4 v = ((const float4*)in)[i];
    bf16x4 o;
    o.x = (__bf16)v.x; o.y = (__bf16)v.y; o.z = (__bf16)v.z; o.w = (__bf16)v.w;
    ((bf16x4*)out)[i] = o;
  }
}

// ---------------------------------------------------------------- GEMM C = A @ B^T + bias
// A: [M][K] bf16 row-major, B: [N][K] bf16 row-major (i.e. B^T input layout).
// m97 recipe: 128x128 tile, BK=32, 256 thr (4 waves, 2x2), global_load_lds w=16,
// per-wave 4x4 grid of 16x16x32 bf16 MFMA.
template <int OUT_BF16>
__global__ __launch_bounds__(256) void gemm_bt(
    const __bf16* __restrict__ A, const __bf16* __restrict__ B,
    const float* __restrict__ bias, void* __restrict__ Cout,
    int M, int N, int K) {
  __shared__ __bf16 As[128 * 32];
  __shared__ __bf16 Bs[128 * 32];
  const int tid = threadIdx.x;
  const int wave = tid >> 6, lane = tid & 63;
  const int quad = lane >> 4, l15 = lane & 15;
  const int wm = (wave & 1) * 64, wn = (wave >> 1) * 64;
  const long row0 = (long)blockIdx.y * 128;
  const long col0 = (long)blockIdx.x * 128;

  floatx4 acc[4][4] = {};

  // staging: issue i covers rows [i*64, i*64+64); wave w rows [w*16,+16)
  const int sr = wave * 16 + (lane >> 2);
  const int sc = (lane & 3) * 8;
  const __bf16* ga = A + (row0 + sr) * (long)K + sc;
  const __bf16* gb = B + (col0 + sr) * (long)K + sc;
  __bf16* lA = As + wave * 512 + lane * 8;   // bytes: wave*1024 + lane*16
  __bf16* lB = Bs + wave * 512 + lane * 8;

  for (int k0 = 0; k0 < K; k0 += 32) {
    gload_lds16(ga,            lA);
    gload_lds16(ga + 64 * (long)K, lA + 2048);
    gload_lds16(gb,            lB);
    gload_lds16(gb + 64 * (long)K, lB + 2048);
    ga += 32; gb += 32;
    __syncthreads();   // drains vmcnt(0): async LDS writes visible

    bf16x8 af[4], bfr[4];
#pragma unroll
    for (int i = 0; i < 4; ++i)
      af[i] = *(const bf16x8*)(As + (wm + i * 16 + l15) * 32 + quad * 8);
#pragma unroll
    for (int j = 0; j < 4; ++j)
      bfr[j] = *(const bf16x8*)(Bs + (wn + j * 16 + l15) * 32 + quad * 8);
#pragma unroll
    for (int i = 0; i < 4; ++i)
#pragma unroll
      for (int j = 0; j < 4; ++j)
        acc[i][j] = MFMA16(af[i], bfr[j], acc[i][j]);
    __syncthreads();
  }

  // epilogue: C/D layout col=lane&15, row=quad*4+reg
#pragma unroll
  for (int i = 0; i < 4; ++i) {
    const long r0 = row0 + wm + i * 16 + quad * 4;
#pragma unroll
    for (int j = 0; j < 4; ++j) {
      const long c = col0 + wn + j * 16 + l15;
      const float bv = bias[c];
#pragma unroll
      for (int reg = 0; reg < 4; ++reg) {
        float v = acc[i][j][reg] + bv;
        if (OUT_BF16) ((__bf16*)Cout)[(r0 + reg) * (long)N + c] = (__bf16)v;
        else          ((float*)Cout)[(r0 + reg) * (long)N + c] = v;
      }
    }
  }
}

// ---------------------------------------------------------------- V transpose
// qkv[b*2048+s][2048 + h*64 + dh] -> Vt[(b*16+h)][dh][s]  (bf16)
__global__ __launch_bounds__(256) void v_transpose(
    const __bf16* __restrict__ qkv, __bf16* __restrict__ Vt) {
  const int st = blockIdx.x, h = blockIdx.y, b = blockIdx.z;
  __shared__ __bf16 T[64][72];
  const int tid = threadIdx.x;
#pragma unroll
  for (int i = 0; i < 2; ++i) {
    int chunk = i * 256 + tid;
    int s = chunk >> 3, c = chunk & 7;
    ushortx8 v = *(const ushortx8*)(qkv + (long)(b * 2048 + st * 64 + s) * 3072
                                    + 2048 + h * 64 + c * 8);
    *(ushortx8*)&T[s][c * 8] = v;
  }
  __syncthreads();
#pragma unroll
  for (int i = 0; i < 2; ++i) {
    int chunk = i * 256 + tid;
    int dh = chunk >> 3, c = chunk & 7;
    ushortx8 v;
#pragma unroll
    for (int j = 0; j < 8; ++j)
      v[j] = *(const unsigned short*)&T[c * 8 + j][dh];
    *(ushortx8*)(Vt + ((long)(b * 16 + h) * 64 + dh) * 2048 + st * 64 + c * 8) = v;
  }
}

// ---------------------------------------------------------------- flash attention
// One block per (b, h, 64-query tile); 4 waves, each owns 16 query rows.
// K tiles of 64 keys; online softmax in exp2 domain; P via per-wave LDS
// round-trip (C-layout -> A-operand layout). LDS rows padded to 72 elements
// (144B) so b128 fragment reads are ~2-way (free) instead of 16-way.
__global__ __launch_bounds__(256) void flash_attn(
    const __bf16* __restrict__ qkv,   // [8192][3072]
    const __bf16* __restrict__ Vt,    // [64][64][2048]
    __bf16* __restrict__ Out) {       // [8192][1024]
  constexpr int S = 2048;
  const int qt = (int)gridDim.x - 1 - (int)blockIdx.x;  // long blocks first
  const int h = blockIdx.y, b = blockIdx.z;
  __shared__ __bf16 Ks[64 * 72];
  __shared__ __bf16 Vs[64 * 72];     // transposed: [dh][key]
  __shared__ __bf16 Ps[4 * 16 * 72]; // per-wave P strip [16 q][64 key]
  const int tid = threadIdx.x, wave = tid >> 6, lane = tid & 63;
  const int quad = lane >> 4, l15 = lane & 15;

  // Q fragments (A-operand: m=lane&15, k=quad*8+j), fixed for whole block
  const long qrow = (long)(b * S + qt * 64 + wave * 16 + l15) * 3072 + h * 64;
  const bf16x8 qf0 = *(const bf16x8*)(qkv + qrow + quad * 8);
  const bf16x8 qf1 = *(const bf16x8*)(qkv + qrow + 32 + quad * 8);

  floatx4 o[4] = {};
  float m_i[4], l_i[4];
#pragma unroll
  for (int r = 0; r < 4; ++r) { m_i[r] = -__builtin_inff(); l_i[r] = 0.f; }

  const __bf16* Kbase = qkv + (long)b * S * 3072 + 1024 + h * 64;
  const __bf16* Vbase = Vt + (long)(b * 16 + h) * 64 * S;
  const int srow = tid >> 3;            // 0..31
  const int sc = (tid & 7) * 8;         // element offset in 64-wide row
  const int qg0 = qt * 64 + wave * 16 + quad * 4;
  const float c_scale = 0.125f * 1.44269504f;  // 1/sqrt(64) * log2(e)

  for (int kt = 0; kt <= qt; ++kt) {
    // stage K [key][dh] and V^T [dh][key], padded stride 72
#pragma unroll
    for (int i = 0; i < 2; ++i) {
      int row = i * 32 + srow;
      ushortx8 kv = *(const ushortx8*)(Kbase + (long)(kt * 64 + row) * 3072 + sc);
      ushortx8 vv = *(const ushortx8*)(Vbase + (long)row * S + kt * 64 + sc);
      *(ushortx8*)(Ks + row * 72 + sc) = kv;
      *(ushortx8*)(Vs + row * 72 + sc) = vv;
    }
    __syncthreads();

    // S = Q @ K^T   (B-operand: n=lane&15 -> key, k=quad*8+j -> dh)
    floatx4 sv[4];
#pragma unroll
    for (int nb = 0; nb < 4; ++nb) {
      bf16x8 k0 = *(const bf16x8*)(Ks + (nb * 16 + l15) * 72 + quad * 8);
      bf16x8 k1 = *(const bf16x8*)(Ks + (nb * 16 + l15) * 72 + 32 + quad * 8);
      floatx4 z = {0.f, 0.f, 0.f, 0.f};
      z = MFMA16(qf0, k0, z);
      z = MFMA16(qf1, k1, z);
      sv[nb] = z;
    }

    // scale into log2 domain + causal mask (diagonal tile only)
    const bool diag = (kt == qt);
    float mt[4];
#pragma unroll
    for (int r = 0; r < 4; ++r) mt[r] = -__builtin_inff();
#pragma unroll
    for (int nb = 0; nb < 4; ++nb) {
      const int keyg = kt * 64 + nb * 16 + l15;
#pragma unroll
      for (int r = 0; r < 4; ++r) {
        float v = sv[nb][r] * c_scale;
        if (diag && keyg > qg0 + r) v = -__builtin_inff();
        sv[nb][r] = v;
        mt[r] = fmaxf(mt[r], v);
      }
    }
#pragma unroll
    for (int x = 1; x <= 8; x <<= 1)
#pragma unroll
      for (int r = 0; r < 4; ++r)
        mt[r] = fmaxf(mt[r], __shfl_xor(mt[r], x, 64));

    float alpha[4], lt[4] = {0.f, 0.f, 0.f, 0.f};
#pragma unroll
    for (int r = 0; r < 4; ++r) {
      float mn = fmaxf(m_i[r], mt[r]);
      alpha[r] = exp2f(m_i[r] - mn);
      m_i[r] = mn;
    }
#pragma unroll
    for (int nb = 0; nb < 4; ++nb)
#pragma unroll
      for (int r = 0; r < 4; ++r) {
        float p = exp2f(sv[nb][r] - m_i[r]);
        sv[nb][r] = p;
        lt[r] += p;
      }

    // P (C-layout) -> per-wave LDS -> A-operand layout
    __bf16* pw = Ps + wave * 16 * 72;
#pragma unroll
    for (int nb = 0; nb < 4; ++nb)
#pragma unroll
      for (int r = 0; r < 4; ++r)
        pw[(quad * 4 + r) * 72 + nb * 16 + l15] = (__bf16)sv[nb][r];

#pragma unroll
    for (int x = 1; x <= 8; x <<= 1)
#pragma unroll
      for (int r = 0; r < 4; ++r)
        lt[r] += __shfl_xor(lt[r], x, 64);
#pragma unroll
    for (int r = 0; r < 4; ++r) l_i[r] = l_i[r] * alpha[r] + lt[r];
#pragma unroll
    for (int nb = 0; nb < 4; ++nb)
#pragma unroll
      for (int r = 0; r < 4; ++r) o[nb][r] *= alpha[r];

    // O += P @ V   (A = P from LDS, B = V^T rows contiguous in key)
    bf16x8 pa0 = *(const bf16x8*)(pw + l15 * 72 + quad * 8);
    bf16x8 pa1 = *(const bf16x8*)(pw + l15 * 72 + 32 + quad * 8);
#pragma unroll
    for (int nb = 0; nb < 4; ++nb) {
      bf16x8 v0 = *(const bf16x8*)(Vs + (nb * 16 + l15) * 72 + quad * 8);
      bf16x8 v1 = *(const bf16x8*)(Vs + (nb * 16 + l15) * 72 + 32 + quad * 8);
      o[nb] = MFMA16(pa0, v0, o[nb]);
      o[nb] = MFMA16(pa1, v1, o[nb]);
    }
    __syncthreads();
  }

  // epilogue: divide by softmax denom, store bf16 [b*S+s][h*64+dh]
  const long orow0 = (long)(b * S + qt * 64 + wave * 16 + quad * 4);
#pragma unroll
  for (int r = 0; r < 4; ++r) {
    const float inv = 1.f / l_i[r];
#pragma unroll
    for (int nb = 0; nb < 4; ++nb)
      Out[(orow0 + r) * 1024 + h * 64 + nb * 16 + l15] =
          (__bf16)(o[nb][r] * inv);
  }
}

// ---------------------------------------------------------------- launch
extern "C" void kernel_launch(void* const* d_in, const int* in_sizes, int n_in,
                              void* d_out, int out_size, void* d_ws, size_t ws_size,
                              hipStream_t stream) {
  const float* x     = (const float*)d_in[0];
  const float* W_in  = (const float*)d_in[1];
  const float* b_in  = (const float*)d_in[2];
  const float* W_out = (const float*)d_in[3];
  const float* b_out = (const float*)d_in[4];

  const int BS = 4 * 2048;   // 8192 rows
  const int D = 1024, N3 = 3072;

  char* w = (char*)d_ws;
  __bf16* xb    = (__bf16*)w;  w += (size_t)BS * D * 2;        // 16 MiB
  __bf16* Winb  = (__bf16*)w;  w += (size_t)N3 * D * 2;        //  6 MiB
  __bf16* Woutb = (__bf16*)w;  w += (size_t)D * D * 2;         //  2 MiB
  __bf16* qkvb  = (__bf16*)w;  w += (size_t)BS * N3 * 2;       // 48 MiB
  __bf16* Vtb   = (__bf16*)w;  w += (size_t)64 * 64 * 2048 * 2;// 16 MiB
  __bf16* attnb = (__bf16*)w;  w += (size_t)BS * D * 2;        // 16 MiB
  // total ~104 MiB of ws

  cast_kernel<<<dim3((BS * D / 4 + 255) / 256), 256, 0, stream>>>(x, xb, BS * D / 4);
  cast_kernel<<<dim3((N3 * D / 4 + 255) / 256), 256, 0, stream>>>(W_in, Winb, N3 * D / 4);
  cast_kernel<<<dim3((D * D / 4 + 255) / 256), 256, 0, stream>>>(W_out, Woutb, D * D / 4);

  gemm_bt<1><<<dim3(N3 / 128, BS / 128), 256, 0, stream>>>(
      xb, Winb, b_in, (void*)qkvb, BS, N3, D);

  v_transpose<<<dim3(32, 16, 4), 256, 0, stream>>>(qkvb, Vtb);

  flash_attn<<<dim3(32, 16, 4), 256, 0, stream>>>(qkvb, Vtb, attnb);

  gemm_bt<0><<<dim3(D / 128, BS / 128), 256, 0, stream>>>(
      attnb, Woutb, b_out, d_out, BS, D, D);
}

// Round 2
// 408.036 us; speedup vs baseline: 1.0792x; 1.0792x over previous
//
#include <hip/hip_runtime.h>
#include <hip/hip_bf16.h>
#include <cstdint>

// Problem: x[4,2048,1024] fp32; qkv = x@W_in^T+b_in; 16-head causal attention
// (dh=64); out = attn@W_out^T + b_out -> fp32 [4,2048,1024].
// Strategy: bf16 MFMA everywhere (threshold 7.4e-2 allows it), fp32 accumulate.
// R2: flash rewrite — Q-tile 128 (2 m-frags/wave), Q pre-scaled into exp2
// domain at cast time, softmax denom via ones-MFMA, register prefetch of K/V.

typedef float  floatx4  __attribute__((ext_vector_type(4)));
typedef __bf16 bf16x8   __attribute__((ext_vector_type(8)));
typedef __bf16 bf16x4   __attribute__((ext_vector_type(4)));
typedef unsigned short ushortx8 __attribute__((ext_vector_type(8)));

#define MFMA16(a,b,c) __builtin_amdgcn_mfma_f32_16x16x32_bf16(a, b, c, 0, 0, 0)

#define C_SCALE 0.18033688011112042f  /* (1/sqrt(64)) * log2(e) */

__device__ __forceinline__ void gload_lds16(const void* g, void* l) {
  __builtin_amdgcn_global_load_lds(
      (__attribute__((address_space(1))) void*)(g),
      (__attribute__((address_space(3))) void*)(l), 16, 0, 0);
}

// ---------------------------------------------------------------- cast fp32->bf16
__global__ __launch_bounds__(256) void cast_kernel(
    const float* __restrict__ in, __bf16* __restrict__ out, int n4) {
  int i = blockIdx.x * 256 + threadIdx.x;
  if (i < n4) {
    const float4 v = ((const float4*)in)[i];
    bf16x4 o;
    o.x = (__bf16)v.x; o.y = (__bf16)v.y; o.z = (__bf16)v.z; o.w = (__bf16)v.w;
    ((bf16x4*)out)[i] = o;
  }
}

// cast W_in with the Q rows (first 1024 of 3072) pre-scaled by C_SCALE so the
// QK^T MFMA emits scores already in the exp2 domain.
__global__ __launch_bounds__(256) void cast_win(
    const float* __restrict__ in, __bf16* __restrict__ out, int n4) {
  int i = blockIdx.x * 256 + threadIdx.x;
  if (i < n4) {
    const float4 v = ((const float4*)in)[i];
    const float s = (i < (1024 * 1024 / 4)) ? C_SCALE : 1.0f;
    bf16x4 o;
    o.x = (__bf16)(v.x * s); o.y = (__bf16)(v.y * s);
    o.z = (__bf16)(v.z * s); o.w = (__bf16)(v.w * s);
    ((bf16x4*)out)[i] = o;
  }
}

__global__ __launch_bounds__(256) void scale_bin(
    const float* __restrict__ in, float* __restrict__ out) {
  int i = blockIdx.x * 256 + threadIdx.x;  // 3072
  out[i] = in[i] * (i < 1024 ? C_SCALE : 1.0f);
}

// ---------------------------------------------------------------- GEMM C = A @ B^T + bias
template <int OUT_BF16>
__global__ __launch_bounds__(256) void gemm_bt(
    const __bf16* __restrict__ A, const __bf16* __restrict__ B,
    const float* __restrict__ bias, void* __restrict__ Cout,
    int M, int N, int K) {
  __shared__ __bf16 As[128 * 32];
  __shared__ __bf16 Bs[128 * 32];
  const int tid = threadIdx.x;
  const int wave = tid >> 6, lane = tid & 63;
  const int quad = lane >> 4, l15 = lane & 15;
  const int wm = (wave & 1) * 64, wn = (wave >> 1) * 64;
  const long row0 = (long)blockIdx.y * 128;
  const long col0 = (long)blockIdx.x * 128;

  floatx4 acc[4][4] = {};

  const int sr = wave * 16 + (lane >> 2);
  const int sc = (lane & 3) * 8;
  const __bf16* ga = A + (row0 + sr) * (long)K + sc;
  const __bf16* gb = B + (col0 + sr) * (long)K + sc;
  __bf16* lA = As + wave * 512 + lane * 8;
  __bf16* lB = Bs + wave * 512 + lane * 8;

  for (int k0 = 0; k0 < K; k0 += 32) {
    gload_lds16(ga,                lA);
    gload_lds16(ga + 64 * (long)K, lA + 2048);
    gload_lds16(gb,                lB);
    gload_lds16(gb + 64 * (long)K, lB + 2048);
    ga += 32; gb += 32;
    __syncthreads();

    bf16x8 af[4], bfr[4];
#pragma unroll
    for (int i = 0; i < 4; ++i)
      af[i] = *(const bf16x8*)(As + (wm + i * 16 + l15) * 32 + quad * 8);
#pragma unroll
    for (int j = 0; j < 4; ++j)
      bfr[j] = *(const bf16x8*)(Bs + (wn + j * 16 + l15) * 32 + quad * 8);
#pragma unroll
    for (int i = 0; i < 4; ++i)
#pragma unroll
      for (int j = 0; j < 4; ++j)
        acc[i][j] = MFMA16(af[i], bfr[j], acc[i][j]);
    __syncthreads();
  }

#pragma unroll
  for (int i = 0; i < 4; ++i) {
    const long r0 = row0 + wm + i * 16 + quad * 4;
#pragma unroll
    for (int j = 0; j < 4; ++j) {
      const long c = col0 + wn + j * 16 + l15;
      const float bv = bias[c];
#pragma unroll
      for (int reg = 0; reg < 4; ++reg) {
        float v = acc[i][j][reg] + bv;
        if (OUT_BF16) ((__bf16*)Cout)[(r0 + reg) * (long)N + c] = (__bf16)v;
        else          ((float*)Cout)[(r0 + reg) * (long)N + c] = v;
      }
    }
  }
}

// ---------------------------------------------------------------- V transpose
__global__ __launch_bounds__(256) void v_transpose(
    const __bf16* __restrict__ qkv, __bf16* __restrict__ Vt) {
  const int st = blockIdx.x, h = blockIdx.y, b = blockIdx.z;
  __shared__ __bf16 T[64][72];
  const int tid = threadIdx.x;
#pragma unroll
  for (int i = 0; i < 2; ++i) {
    int chunk = i * 256 + tid;
    int s = chunk >> 3, c = chunk & 7;
    ushortx8 v = *(const ushortx8*)(qkv + (long)(b * 2048 + st * 64 + s) * 3072
                                    + 2048 + h * 64 + c * 8);
    *(ushortx8*)&T[s][c * 8] = v;
  }
  __syncthreads();
#pragma unroll
  for (int i = 0; i < 2; ++i) {
    int chunk = i * 256 + tid;
    int dh = chunk >> 3, c = chunk & 7;
    ushortx8 v;
#pragma unroll
    for (int j = 0; j < 8; ++j)
      v[j] = *(const unsigned short*)&T[c * 8 + j][dh];
    *(ushortx8*)(Vt + ((long)(b * 16 + h) * 64 + dh) * 2048 + st * 64 + c * 8) = v;
  }
}

// ---------------------------------------------------------------- flash attention
// Block = (b, h, 128-query tile); 4 waves; wave owns 32 q rows as 2 m-frags
// (rows wave*16..+15 and +64..+79). K-tile 64. Scores arrive pre-scaled in the
// exp2 domain (Q scaled at cast). Softmax denominator via ones-MFMA. K/V tiles
// register-prefetched one iteration ahead.
__global__ __launch_bounds__(256) void flash_attn(
    const __bf16* __restrict__ qkv,   // [8192][3072]
    const __bf16* __restrict__ Vt,    // [64][64][2048]
    __bf16* __restrict__ Out) {       // [8192][1024]
  constexpr int S = 2048;
  const int qt = (int)gridDim.x - 1 - (int)blockIdx.x;  // 0..15, long first
  const int h = blockIdx.y, b = blockIdx.z;
  __shared__ __bf16 Ks[64 * 72];
  __shared__ __bf16 Vs[64 * 72];       // [dh][key]
  __shared__ __bf16 Ps[4 * 32 * 72];   // per-wave strip: [32 q][64 key]
  const int tid = threadIdx.x, wave = tid >> 6, lane = tid & 63;
  const int quad = lane >> 4, l15 = lane & 15;

  // Q A-frags (m=l15, k=quad*8+j); mi selects row group wave*16 + mi*64
  const long qr = (long)(b * S + qt * 128 + wave * 16 + l15) * 3072 + h * 64;
  bf16x8 qf[2][2];
#pragma unroll
  for (int mi = 0; mi < 2; ++mi) {
    qf[mi][0] = *(const bf16x8*)(qkv + qr + (long)mi * 64 * 3072 + quad * 8);
    qf[mi][1] = *(const bf16x8*)(qkv + qr + (long)mi * 64 * 3072 + 32 + quad * 8);
  }

  bf16x8 ones;
#pragma unroll
  for (int j = 0; j < 8; ++j) ones[j] = (__bf16)1.0f;

  floatx4 o[2][4] = {};
  float m_i[2][4], l_i[2][4];
#pragma unroll
  for (int mi = 0; mi < 2; ++mi)
#pragma unroll
    for (int r = 0; r < 4; ++r) { m_i[mi][r] = -1.0e30f; l_i[mi][r] = 0.f; }

  // staging addresses: thread covers rows srow and srow+32, 16B chunk sc8
  const int srow = tid >> 3;           // 0..31
  const int sc8 = (tid & 7) * 8;
  const __bf16* ka0 = qkv + (long)b * S * 3072 + 1024 + h * 64
                      + (long)srow * 3072 + sc8;
  const __bf16* ka1 = ka0 + 32 * 3072;
  const __bf16* va0 = Vt + (long)(b * 16 + h) * 64 * S + (long)srow * S + sc8;
  const __bf16* va1 = va0 + 32 * S;

  const int kmax = 2 * qt + 2;

  // prefetch tile 0
  ushortx8 kr0 = *(const ushortx8*)ka0;  ka0 += 64 * 3072;
  ushortx8 kr1 = *(const ushortx8*)ka1;  ka1 += 64 * 3072;
  ushortx8 vr0 = *(const ushortx8*)va0;  va0 += 64;
  ushortx8 vr1 = *(const ushortx8*)va1;  va1 += 64;

  __bf16* pw = Ps + wave * 32 * 72;

  for (int kt = 0; kt < kmax; ++kt) {
    __syncthreads();                    // prev iter's LDS reads complete
    *(ushortx8*)(Ks + srow * 72 + sc8)        = kr0;
    *(ushortx8*)(Ks + (32 + srow) * 72 + sc8) = kr1;
    *(ushortx8*)(Vs + srow * 72 + sc8)        = vr0;
    *(ushortx8*)(Vs + (32 + srow) * 72 + sc8) = vr1;
    if (kt + 1 < kmax) {                // prefetch next tile (hidden by compute)
      kr0 = *(const ushortx8*)ka0;  ka0 += 64 * 3072;
      kr1 = *(const ushortx8*)ka1;  ka1 += 64 * 3072;
      vr0 = *(const ushortx8*)va0;  va0 += 64;
      vr1 = *(const ushortx8*)va1;  va1 += 64;
    }
    __syncthreads();                    // staging visible

    const int rel = kt - 2 * qt;        // <0 bulk; 0: mask mi0; 1: skip mi0, mask mi1
    const bool skip0 = rel >= 1;

    // S = Q @ K^T  (scores already in exp2 domain)
    floatx4 sv[2][4];
#pragma unroll
    for (int nb = 0; nb < 4; ++nb) {
      const bf16x8 k0 = *(const bf16x8*)(Ks + (nb * 16 + l15) * 72 + quad * 8);
      const bf16x8 k1 = *(const bf16x8*)(Ks + (nb * 16 + l15) * 72 + 32 + quad * 8);
      if (!skip0) {
        floatx4 z = {0.f, 0.f, 0.f, 0.f};
        z = MFMA16(qf[0][0], k0, z);
        z = MFMA16(qf[0][1], k1, z);
        sv[0][nb] = z;
      }
      floatx4 z1 = {0.f, 0.f, 0.f, 0.f};
      z1 = MFMA16(qf[1][0], k0, z1);
      z1 = MFMA16(qf[1][1], k1, z1);
      sv[1][nb] = z1;
    }

    // causal mask, only on the (at most one) partial m-frag
    if (rel == 0 || rel == 1) {
      const int mim = rel;              // the masked frag
      const int qrow0 = qt * 128 + mim * 64 + wave * 16 + quad * 4;
#pragma unroll
      for (int nb = 0; nb < 4; ++nb) {
        const int keyg = kt * 64 + nb * 16 + l15;
#pragma unroll
        for (int r = 0; r < 4; ++r)
          if (keyg > qrow0 + r) sv[mim][nb][r] = -1.0e30f;
      }
    }

#pragma unroll
    for (int mi = 0; mi < 2; ++mi) {
      if (mi == 0 && skip0) continue;

      // row max (C-layout: row=quad*4+r, keys across l15 and nb)
      float mt[4];
#pragma unroll
      for (int r = 0; r < 4; ++r) mt[r] = -1.0e30f;
#pragma unroll
      for (int nb = 0; nb < 4; ++nb)
#pragma unroll
        for (int r = 0; r < 4; ++r) mt[r] = fmaxf(mt[r], sv[mi][nb][r]);
#pragma unroll
      for (int x = 1; x <= 8; x <<= 1)
#pragma unroll
        for (int r = 0; r < 4; ++r)
          mt[r] = fmaxf(mt[r], __shfl_xor(mt[r], x, 64));

      float alpha[4];
#pragma unroll
      for (int r = 0; r < 4; ++r) {
        const float mn = fmaxf(m_i[mi][r], mt[r]);
        alpha[r] = exp2f(m_i[mi][r] - mn);
        m_i[mi][r] = mn;
      }

      // P = exp2(S - m), straight to this wave's LDS strip (C->A layout xform)
#pragma unroll
      for (int nb = 0; nb < 4; ++nb)
#pragma unroll
        for (int r = 0; r < 4; ++r) {
          const float p = exp2f(sv[mi][nb][r] - m_i[mi][r]);
          pw[(mi * 16 + quad * 4 + r) * 72 + nb * 16 + l15] = (__bf16)p;
        }

      // A-frags of P (same-wave LDS round trip; compiler orders via lgkmcnt)
      const bf16x8 pa0 = *(const bf16x8*)(pw + (mi * 16 + l15) * 72 + quad * 8);
      const bf16x8 pa1 = *(const bf16x8*)(pw + (mi * 16 + l15) * 72 + 32 + quad * 8);

      // softmax denominator tile-sum via ones-MFMA (replicated across lanes)
      floatx4 lacc = {0.f, 0.f, 0.f, 0.f};
      lacc = MFMA16(pa0, ones, lacc);
      lacc = MFMA16(pa1, ones, lacc);
#pragma unroll
      for (int r = 0; r < 4; ++r)
        l_i[mi][r] = l_i[mi][r] * alpha[r] + lacc[r];

#pragma unroll
      for (int nb = 0; nb < 4; ++nb)
#pragma unroll
        for (int r = 0; r < 4; ++r) o[mi][nb][r] *= alpha[r];

      // O += P @ V
#pragma unroll
      for (int nb = 0; nb < 4; ++nb) {
        const bf16x8 v0 = *(const bf16x8*)(Vs + (nb * 16 + l15) * 72 + quad * 8);
        const bf16x8 v1 = *(const bf16x8*)(Vs + (nb * 16 + l15) * 72 + 32 + quad * 8);
        o[mi][nb] = MFMA16(pa0, v0, o[mi][nb]);
        o[mi][nb] = MFMA16(pa1, v1, o[mi][nb]);
      }
    }
  }

  // epilogue
#pragma unroll
  for (int mi = 0; mi < 2; ++mi) {
    const long orow0 = (long)(b * S + qt * 128 + mi * 64 + wave * 16 + quad * 4);
#pragma unroll
    for (int r = 0; r < 4; ++r) {
      const float inv = 1.f / l_i[mi][r];
#pragma unroll
      for (int nb = 0; nb < 4; ++nb)
        Out[(orow0 + r) * 1024 + h * 64 + nb * 16 + l15] =
            (__bf16)(o[mi][nb][r] * inv);
    }
  }
}

// ---------------------------------------------------------------- launch
extern "C" void kernel_launch(void* const* d_in, const int* in_sizes, int n_in,
                              void* d_out, int out_size, void* d_ws, size_t ws_size,
                              hipStream_t stream) {
  const float* x     = (const float*)d_in[0];
  const float* W_in  = (const float*)d_in[1];
  const float* b_in  = (const float*)d_in[2];
  const float* W_out = (const float*)d_in[3];
  const float* b_out = (const float*)d_in[4];

  const int BS = 4 * 2048;   // 8192 rows
  const int D = 1024, N3 = 3072;

  char* w = (char*)d_ws;
  __bf16* xb    = (__bf16*)w;  w += (size_t)BS * D * 2;        // 16 MiB
  __bf16* Winb  = (__bf16*)w;  w += (size_t)N3 * D * 2;        //  6 MiB
  __bf16* Woutb = (__bf16*)w;  w += (size_t)D * D * 2;         //  2 MiB
  __bf16* qkvb  = (__bf16*)w;  w += (size_t)BS * N3 * 2;       // 48 MiB
  __bf16* Vtb   = (__bf16*)w;  w += (size_t)64 * 64 * 2048 * 2;// 16 MiB
  __bf16* attnb = (__bf16*)w;  w += (size_t)BS * D * 2;        // 16 MiB
  float*  bins  = (float*)w;   w += (size_t)N3 * 4;            // 12 KiB

  cast_kernel<<<dim3((BS * D / 4 + 255) / 256), 256, 0, stream>>>(x, xb, BS * D / 4);
  cast_win   <<<dim3((N3 * D / 4 + 255) / 256), 256, 0, stream>>>(W_in, Winb, N3 * D / 4);
  cast_kernel<<<dim3((D * D / 4 + 255) / 256), 256, 0, stream>>>(W_out, Woutb, D * D / 4);
  scale_bin  <<<dim3(N3 / 256), 256, 0, stream>>>(b_in, bins);

  gemm_bt<1><<<dim3(N3 / 128, BS / 128), 256, 0, stream>>>(
      xb, Winb, bins, (void*)qkvb, BS, N3, D);

  v_transpose<<<dim3(32, 16, 4), 256, 0, stream>>>(qkvb, Vtb);

  flash_attn<<<dim3(16, 16, 4), 256, 0, stream>>>(qkvb, Vtb, attnb);

  gemm_bt<0><<<dim3(D / 128, BS / 128), 256, 0, stream>>>(
      attnb, Woutb, b_out, d_out, BS, D, D);
}

// Round 3
// 301.458 us; speedup vs baseline: 1.4608x; 1.3535x over previous
//
#include <hip/hip_runtime.h>
#include <hip/hip_bf16.h>
#include <cstdint>

// Problem: x[4,2048,1024] fp32; qkv = x@W_in^T+b_in; 16-head causal attention
// (dh=64); out = attn@W_out^T + b_out -> fp32 [4,2048,1024].
// R3: flash with triangle-paired q-tiles (x, 15-x) sharing one K-loop
// (uniform 34 q-set-iterations per block -> perfect balance), single-barrier
// double-buffered K/V staging, V-transpose fused into gemm1 epilogue.

typedef float  floatx4  __attribute__((ext_vector_type(4)));
typedef __bf16 bf16x8   __attribute__((ext_vector_type(8)));
typedef __bf16 bf16x4   __attribute__((ext_vector_type(4)));
typedef unsigned short ushortx8 __attribute__((ext_vector_type(8)));

#define MFMA16(a,b,c) __builtin_amdgcn_mfma_f32_16x16x32_bf16(a, b, c, 0, 0, 0)

#define C_SCALE 0.18033688011112042f  /* (1/sqrt(64)) * log2(e) */

__device__ __forceinline__ void gload_lds16(const void* g, void* l) {
  __builtin_amdgcn_global_load_lds(
      (__attribute__((address_space(1))) void*)(g),
      (__attribute__((address_space(3))) void*)(l), 16, 0, 0);
}

// ---------------------------------------------------------------- casts
__global__ __launch_bounds__(256) void cast_kernel(
    const float* __restrict__ in, __bf16* __restrict__ out, int n4) {
  int i = blockIdx.x * 256 + threadIdx.x;
  if (i < n4) {
    const float4 v = ((const float4*)in)[i];
    bf16x4 o;
    o.x = (__bf16)v.x; o.y = (__bf16)v.y; o.z = (__bf16)v.z; o.w = (__bf16)v.w;
    ((bf16x4*)out)[i] = o;
  }
}

// W_in cast with Q rows (first 1024 of 3072) pre-scaled by C_SCALE so QK^T
// emits scores already in the exp2 domain.
__global__ __launch_bounds__(256) void cast_win(
    const float* __restrict__ in, __bf16* __restrict__ out, int n4) {
  int i = blockIdx.x * 256 + threadIdx.x;
  if (i < n4) {
    const float4 v = ((const float4*)in)[i];
    const float s = (i < (1024 * 1024 / 4)) ? C_SCALE : 1.0f;
    bf16x4 o;
    o.x = (__bf16)(v.x * s); o.y = (__bf16)(v.y * s);
    o.z = (__bf16)(v.z * s); o.w = (__bf16)(v.w * s);
    ((bf16x4*)out)[i] = o;
  }
}

__global__ __launch_bounds__(256) void scale_bin(
    const float* __restrict__ in, float* __restrict__ out) {
  int i = blockIdx.x * 256 + threadIdx.x;  // 3072
  out[i] = in[i] * (i < 1024 ? C_SCALE : 1.0f);
}

// ---------------------------------------------------------------- GEMM C = A @ B^T + bias
// MODE 0: fp32 out. MODE 2: qkv — Q/K cols (<2048) stored bf16 row-major,
// V cols (>=2048) stored transposed into Vt[(b*16+h)*64+dh][s] (8B packed).
template <int MODE>
__global__ __launch_bounds__(256) void gemm_bt(
    const __bf16* __restrict__ A, const __bf16* __restrict__ B,
    const float* __restrict__ bias, void* __restrict__ Cout,
    __bf16* __restrict__ Vt, int M, int N, int K) {
  __shared__ __bf16 As[128 * 32];
  __shared__ __bf16 Bs[128 * 32];
  const int tid = threadIdx.x;
  const int wave = tid >> 6, lane = tid & 63;
  const int quad = lane >> 4, l15 = lane & 15;
  const int wm = (wave & 1) * 64, wn = (wave >> 1) * 64;
  const long row0 = (long)blockIdx.y * 128;
  const long col0 = (long)blockIdx.x * 128;

  floatx4 acc[4][4] = {};

  const int sr = wave * 16 + (lane >> 2);
  const int sc = (lane & 3) * 8;
  const __bf16* ga = A + (row0 + sr) * (long)K + sc;
  const __bf16* gb = B + (col0 + sr) * (long)K + sc;
  __bf16* lA = As + wave * 512 + lane * 8;
  __bf16* lB = Bs + wave * 512 + lane * 8;

  for (int k0 = 0; k0 < K; k0 += 32) {
    gload_lds16(ga,                lA);
    gload_lds16(ga + 64 * (long)K, lA + 2048);
    gload_lds16(gb,                lB);
    gload_lds16(gb + 64 * (long)K, lB + 2048);
    ga += 32; gb += 32;
    __syncthreads();

    bf16x8 af[4], bfr[4];
#pragma unroll
    for (int i = 0; i < 4; ++i)
      af[i] = *(const bf16x8*)(As + (wm + i * 16 + l15) * 32 + quad * 8);
#pragma unroll
    for (int j = 0; j < 4; ++j)
      bfr[j] = *(const bf16x8*)(Bs + (wn + j * 16 + l15) * 32 + quad * 8);
#pragma unroll
    for (int i = 0; i < 4; ++i)
#pragma unroll
      for (int j = 0; j < 4; ++j)
        acc[i][j] = MFMA16(af[i], bfr[j], acc[i][j]);
    __syncthreads();
  }

#pragma unroll
  for (int i = 0; i < 4; ++i) {
    const long r0 = row0 + wm + i * 16 + quad * 4;
#pragma unroll
    for (int j = 0; j < 4; ++j) {
      const long c = col0 + wn + j * 16 + l15;
      const float bv = bias[c];
      if (MODE == 0) {
#pragma unroll
        for (int reg = 0; reg < 4; ++reg)
          ((float*)Cout)[(r0 + reg) * (long)N + c] = acc[i][j][reg] + bv;
      } else {
        if (c < 2048) {
#pragma unroll
          for (int reg = 0; reg < 4; ++reg)
            ((__bf16*)Cout)[(r0 + reg) * (long)N + c] =
                (__bf16)(acc[i][j][reg] + bv);
        } else {
          const int cc = (int)c - 2048;
          const int hh = cc >> 6, dh = cc & 63;
          const int bb = (int)(r0 >> 11), s = (int)(r0 & 2047);
          bf16x4 pk;
#pragma unroll
          for (int reg = 0; reg < 4; ++reg)
            pk[reg] = (__bf16)(acc[i][j][reg] + bv);
          *(bf16x4*)(Vt + ((long)(bb * 16 + hh) * 64 + dh) * 2048 + s) = pk;
        }
      }
    }
  }
}

// ---------------------------------------------------------------- flash attention
// Block = (x, h, b), 512 thr (8 waves). Processes q-tiles qtA=x and qtB=15-x
// in ONE k-loop sharing staged K/V. Wave w owns q rows [qt*128+w*16, +16) for
// each q-set. kmaxA=2x+2 <= kmax=32-2x; total q-set-iters = 34 (uniform).
// Single barrier per iter: store prefetched tile -> buf^1, prefetch tile+2,
// compute from buf, barrier.
__global__ __launch_bounds__(512, 4) void flash_attn(
    const __bf16* __restrict__ qkv,   // [8192][3072]
    const __bf16* __restrict__ Vt,    // [64][64][2048]
    __bf16* __restrict__ Out) {       // [8192][1024]
  constexpr int S = 2048;
  const int x = blockIdx.x;           // 0..7
  const int h = blockIdx.y, b = blockIdx.z;
  const int qtA = x, qtB = 15 - x;
  const int kmaxA = 2 * qtA + 2;
  const int kmax  = 2 * qtB + 2;      // wall iterations (>= 18)

  __shared__ __bf16 Ks[2][64 * 72];
  __shared__ __bf16 Vs[2][64 * 72];   // [dh][key]
  __shared__ __bf16 Ps[8 * 16 * 72];  // per-wave strip [16 q][64 key]

  const int tid = threadIdx.x, wave = tid >> 6, lane = tid & 63;
  const int quad = lane >> 4, l15 = lane & 15;

  // Q A-frags (m=l15, k=quad*8+j) for both q-sets
  bf16x8 qf[2][2];
  {
    const long qrA = (long)(b * S + qtA * 128 + wave * 16 + l15) * 3072 + h * 64;
    const long qrB = (long)(b * S + qtB * 128 + wave * 16 + l15) * 3072 + h * 64;
    qf[0][0] = *(const bf16x8*)(qkv + qrA + quad * 8);
    qf[0][1] = *(const bf16x8*)(qkv + qrA + 32 + quad * 8);
    qf[1][0] = *(const bf16x8*)(qkv + qrB + quad * 8);
    qf[1][1] = *(const bf16x8*)(qkv + qrB + 32 + quad * 8);
  }

  bf16x8 ones;
#pragma unroll
  for (int j = 0; j < 8; ++j) ones[j] = (__bf16)1.0f;

  floatx4 o[2][4] = {};
  float m_i[2][4], l_i[2][4];
#pragma unroll
  for (int st = 0; st < 2; ++st)
#pragma unroll
    for (int r = 0; r < 4; ++r) { m_i[st][r] = -1.0e30f; l_i[st][r] = 0.f; }

  // staging: 512 threads cover one 64x64 K tile + one 64x64 V tile in 16B chunks
  const int srow = tid >> 3;          // 0..63
  const int sc8 = (tid & 7) * 8;
  const __bf16* ka = qkv + ((long)(b * S) + srow) * 3072 + 1024 + h * 64 + sc8;
  const __bf16* va = Vt + ((long)(b * 16 + h) * 64 + srow) * S + sc8;
  const int sl = srow * 72 + sc8;

  __bf16* pw = Ps + wave * 16 * 72;

  // prologue: tile 0 -> buf0; prefetch tile 1
  ushortx8 kr = *(const ushortx8*)ka;
  ushortx8 vr = *(const ushortx8*)va;
  *(ushortx8*)(&Ks[0][sl]) = kr;
  *(ushortx8*)(&Vs[0][sl]) = vr;
  kr = *(const ushortx8*)(ka + (long)64 * 3072);
  vr = *(const ushortx8*)(va + 64);
  __syncthreads();

  for (int kt = 0; kt < kmax; ++kt) {
    const int cur = kt & 1;
    if (kt + 1 < kmax) {               // store tile kt+1 (prev reads of buf^1
      *(ushortx8*)(&Ks[cur ^ 1][sl]) = kr;   // completed before last barrier)
      *(ushortx8*)(&Vs[cur ^ 1][sl]) = vr;
    }
    if (kt + 2 < kmax) {               // prefetch tile kt+2
      kr = *(const ushortx8*)(ka + (long)(kt + 2) * 64 * 3072);
      vr = *(const ushortx8*)(va + (kt + 2) * 64);
    }

#pragma unroll
    for (int set = 0; set < 2; ++set) {
      const int qt = set ? qtB : qtA;
      if (!set && kt >= kmaxA) continue;          // q-set A finished
      const int dlo = 2 * qt, dhi = dlo + 1;
      if (kt == dhi && wave < 4) continue;        // fully masked rows
      const bool part = (kt == dlo && wave < 4) || (kt == dhi && wave >= 4);

      // S = Q @ K^T (already in exp2 domain)
      floatx4 sv[4];
#pragma unroll
      for (int nb = 0; nb < 4; ++nb) {
        const bf16x8 k0 = *(const bf16x8*)(&Ks[cur][(nb * 16 + l15) * 72 + quad * 8]);
        const bf16x8 k1 = *(const bf16x8*)(&Ks[cur][(nb * 16 + l15) * 72 + 32 + quad * 8]);
        floatx4 z = {0.f, 0.f, 0.f, 0.f};
        z = MFMA16(qf[set][0], k0, z);
        z = MFMA16(qf[set][1], k1, z);
        sv[nb] = z;
      }

      if (part) {
        const int q0 = qt * 128 + wave * 16 + quad * 4;
#pragma unroll
        for (int nb = 0; nb < 4; ++nb) {
          const int keyg = kt * 64 + nb * 16 + l15;
#pragma unroll
          for (int r = 0; r < 4; ++r)
            if (keyg > q0 + r) sv[nb][r] = -1.0e30f;
        }
      }

      // row max across l15 (16 lanes)
      float mt[4];
#pragma unroll
      for (int r = 0; r < 4; ++r) mt[r] = -1.0e30f;
#pragma unroll
      for (int nb = 0; nb < 4; ++nb)
#pragma unroll
        for (int r = 0; r < 4; ++r) mt[r] = fmaxf(mt[r], sv[nb][r]);
#pragma unroll
      for (int xm = 1; xm <= 8; xm <<= 1)
#pragma unroll
        for (int r = 0; r < 4; ++r)
          mt[r] = fmaxf(mt[r], __shfl_xor(mt[r], xm, 64));

      float alpha[4];
#pragma unroll
      for (int r = 0; r < 4; ++r) {
        const float mn = fmaxf(m_i[set][r], mt[r]);
        alpha[r] = exp2f(m_i[set][r] - mn);
        m_i[set][r] = mn;
      }

      // P = exp2(S - m) -> per-wave LDS strip (C-layout -> A-layout xform)
#pragma unroll
      for (int nb = 0; nb < 4; ++nb)
#pragma unroll
        for (int r = 0; r < 4; ++r)
          pw[(quad * 4 + r) * 72 + nb * 16 + l15] =
              (__bf16)exp2f(sv[nb][r] - m_i[set][r]);

      const bf16x8 pa0 = *(const bf16x8*)(pw + l15 * 72 + quad * 8);
      const bf16x8 pa1 = *(const bf16x8*)(pw + l15 * 72 + 32 + quad * 8);

      // denominator tile-sum via ones-MFMA
      floatx4 lacc = {0.f, 0.f, 0.f, 0.f};
      lacc = MFMA16(pa0, ones, lacc);
      lacc = MFMA16(pa1, ones, lacc);
#pragma unroll
      for (int r = 0; r < 4; ++r)
        l_i[set][r] = l_i[set][r] * alpha[r] + lacc[r];

#pragma unroll
      for (int nb = 0; nb < 4; ++nb)
#pragma unroll
        for (int r = 0; r < 4; ++r) o[set][nb][r] *= alpha[r];

      // O += P @ V
#pragma unroll
      for (int nb = 0; nb < 4; ++nb) {
        const bf16x8 v0 = *(const bf16x8*)(&Vs[cur][(nb * 16 + l15) * 72 + quad * 8]);
        const bf16x8 v1 = *(const bf16x8*)(&Vs[cur][(nb * 16 + l15) * 72 + 32 + quad * 8]);
        o[set][nb] = MFMA16(pa0, v0, o[set][nb]);
        o[set][nb] = MFMA16(pa1, v1, o[set][nb]);
      }
    }
    __syncthreads();
  }

  // epilogue
#pragma unroll
  for (int set = 0; set < 2; ++set) {
    const int qt = set ? qtB : qtA;
    const long orow0 = (long)(b * S + qt * 128 + wave * 16 + quad * 4);
#pragma unroll
    for (int r = 0; r < 4; ++r) {
      const float inv = 1.f / l_i[set][r];
#pragma unroll
      for (int nb = 0; nb < 4; ++nb)
        Out[(orow0 + r) * 1024 + h * 64 + nb * 16 + l15] =
            (__bf16)(o[set][nb][r] * inv);
    }
  }
}

// ---------------------------------------------------------------- launch
extern "C" void kernel_launch(void* const* d_in, const int* in_sizes, int n_in,
                              void* d_out, int out_size, void* d_ws, size_t ws_size,
                              hipStream_t stream) {
  const float* x     = (const float*)d_in[0];
  const float* W_in  = (const float*)d_in[1];
  const float* b_in  = (const float*)d_in[2];
  const float* W_out = (const float*)d_in[3];
  const float* b_out = (const float*)d_in[4];

  const int BS = 4 * 2048;   // 8192 rows
  const int D = 1024, N3 = 3072;

  char* w = (char*)d_ws;
  __bf16* xb    = (__bf16*)w;  w += (size_t)BS * D * 2;        // 16 MiB
  __bf16* Winb  = (__bf16*)w;  w += (size_t)N3 * D * 2;        //  6 MiB
  __bf16* Woutb = (__bf16*)w;  w += (size_t)D * D * 2;         //  2 MiB
  __bf16* qkvb  = (__bf16*)w;  w += (size_t)BS * N3 * 2;       // 48 MiB
  __bf16* Vtb   = (__bf16*)w;  w += (size_t)64 * 64 * 2048 * 2;// 16 MiB
  __bf16* attnb = (__bf16*)w;  w += (size_t)BS * D * 2;        // 16 MiB
  float*  bins  = (float*)w;   w += (size_t)N3 * 4;            // 12 KiB

  cast_kernel<<<dim3((BS * D / 4 + 255) / 256), 256, 0, stream>>>(x, xb, BS * D / 4);
  cast_win   <<<dim3((N3 * D / 4 + 255) / 256), 256, 0, stream>>>(W_in, Winb, N3 * D / 4);
  cast_kernel<<<dim3((D * D / 4 + 255) / 256), 256, 0, stream>>>(W_out, Woutb, D * D / 4);
  scale_bin  <<<dim3(N3 / 256), 256, 0, stream>>>(b_in, bins);

  gemm_bt<2><<<dim3(N3 / 128, BS / 128), 256, 0, stream>>>(
      xb, Winb, bins, (void*)qkvb, Vtb, BS, N3, D);

  flash_attn<<<dim3(8, 16, 4), 512, 0, stream>>>(qkvb, Vtb, attnb);

  gemm_bt<0><<<dim3(D / 128, BS / 128), 256, 0, stream>>>(
      attnb, Woutb, b_out, d_out, nullptr, BS, D, D);
}